// Round 1
// baseline (177.359 us; speedup 1.0000x reference)
//
#include <hip/hip_runtime.h>

#define T_DIM 1024
#define B_DIM 8
#define IN_DIM 1024
#define OUT_DIM 1024
#define N_MODL 16
#define K_SEL 2

typedef unsigned short ushort_t;
typedef __bf16 bf16x8 __attribute__((ext_vector_type(8)));
typedef float f32x4 __attribute__((ext_vector_type(4)));

__device__ __forceinline__ unsigned int f2bf2(float lo, float hi) {
  union { float f; unsigned int u; } a, b; a.f = lo; b.f = hi;
  unsigned int ra = (a.u + 0x7fffu + ((a.u >> 16) & 1u)) >> 16;
  unsigned int rb = (b.u + 0x7fffu + ((b.u >> 16) & 1u)) >> 16;
  return ra | (rb << 16);
}

__device__ __forceinline__ void async_g2l(const void* g, void* l) {
  __builtin_amdgcn_global_load_lds(
      (const __attribute__((address_space(1))) unsigned int*)g,
      (__attribute__((address_space(3))) unsigned int*)l,
      16, 0, 0);
}

__device__ __forceinline__ int read_sel(const int* __restrict__ s, int g) {
  bool i64 = true;
#pragma unroll
  for (int j = 0; j < 8; ++j) i64 &= (s[2 * j + 1] == 0);
  return i64 ? s[2 * g] : s[g];
}

// Blocks [0,1024): W [16,IN,OUT] f32 -> Wt [16,OUT,IN] bf16, 128x128 tiles,
//   bf16-in-LDS with XOR swizzle, skipping experts not present in selection.
// Blocks [1024,5120): x [T,B,IN] f32 -> bf16 stream convert (same layout).
__global__ __launch_bounds__(256) void convert_kernel(const float* __restrict__ x,
                                                      const float* __restrict__ w,
                                                      const int* __restrict__ selp,
                                                      ushort_t* __restrict__ xb,
                                                      ushort_t* __restrict__ wt) {
  __shared__ ushort_t tb[128 * 128];   // 32KB
  const int bid = blockIdx.x;
  if (bid >= 1024) {
    const int i = (bid - 1024) * 256 + threadIdx.x;
    const float4* s = (const float4*)x;
    float4 a = s[i * 2], b = s[i * 2 + 1];
    uint4 o;
    o.x = f2bf2(a.x, a.y); o.y = f2bf2(a.z, a.w);
    o.z = f2bf2(b.x, b.y); o.w = f2bf2(b.z, b.w);
    ((uint4*)xb)[i] = o;
    return;
  }
  const int m = bid >> 6;
  bool used = false;
#pragma unroll
  for (int g = 0; g < B_DIM * K_SEL; ++g) used |= (read_sel(selp, g) == m);
  if (!used) return;

  const int i0 = ((bid >> 3) & 7) * 128;
  const int o0 = (bid & 7) * 128;
  const float* src = w + ((size_t)(m * IN_DIM + i0)) * OUT_DIM + o0;

  const int o4 = (threadIdx.x & 31) * 4;
  const int ib = threadIdx.x >> 5;
#pragma unroll
  for (int p = 0; p < 16; ++p) {
    const int i = ib + p * 8;
    float4 v = *(const float4*)(src + (size_t)i * OUT_DIM + o4);
    const int osw = o4 ^ (((i >> 3) & 15) << 2);
    uint2 d2; d2.x = f2bf2(v.x, v.y); d2.y = f2bf2(v.z, v.w);
    *(uint2*)(tb + i * 128 + osw) = d2;
  }
  __syncthreads();

  ushort_t* dst = wt + ((size_t)(m * OUT_DIM + o0)) * IN_DIM + i0;
  const int il = (threadIdx.x & 15) * 8;
  const int ob = threadIdx.x >> 4;
  const int q2 = ((il >> 3) & 15) << 2;
#pragma unroll
  for (int p = 0; p < 8; ++p) {
    const int o = ob + p * 16;
    const int osw = o ^ q2;
    uint4 d;
    unsigned int u[8];
#pragma unroll
    for (int j = 0; j < 8; ++j) u[j] = tb[(il + j) * 128 + osw];
    d.x = u[0] | (u[1] << 16); d.y = u[2] | (u[3] << 16);
    d.z = u[4] | (u[5] << 16); d.w = u[6] | (u[7] << 16);
    *(uint4*)(dst + (size_t)o * IN_DIM + il) = d;
  }
}

#define MFMA16 __builtin_amdgcn_mfma_f32_16x16x32_bf16

// One pipelined K-step of the 256x256 tile. 4 phases x 16 MFMA per wave.
// SN:  stage A1,A3 of tile s+1 into nxt buffer (phases 1,2)
// SN2: stage A0,A2,B0..B3 of tile s+2 into cur buffer (phases 3,4) --
//      legal: those regions' last reads complete by the phase-2 barrier.
// WV/W0: s_waitcnt vmcnt(6 or 0) once per step, before the closing barrier.
template<bool SN, bool SN2, bool WV, bool W0>
__device__ __forceinline__ void gemm_step(
    int s, ushort_t* curA, ushort_t* curB, ushort_t* nxtA, ushort_t* nxtB,
    const ushort_t* aS, const ushort_t* bS, int stLds,
    int ardo, int brdo, int cb, f32x4 (&acc)[8][4]) {
  const int k0n  = (s + 1) << 6;
  const int k0n2 = (s + 2) << 6;
  const ushort_t* Ard = curA + ardo;
  const ushort_t* Brd = curB + brdo;
  bf16x8 bf0[4], bf1[4], af[4];

  // ---- phase 1: kk=0, m0-3; load B kk0; stage A1(s+1)
#pragma unroll
  for (int i = 0; i < 4; ++i) af[i] = *(const bf16x8*)(Ard + i * 1024 + cb);
#pragma unroll
  for (int n = 0; n < 4; ++n) bf0[n] = *(const bf16x8*)(Brd + n * 1024 + cb);
  if (SN) async_g2l(aS + (size_t)64 * 8192 + k0n, nxtA + 4096 + stLds);
  __builtin_amdgcn_sched_barrier(0);
  __builtin_amdgcn_s_barrier();
  asm volatile("s_waitcnt lgkmcnt(0)" ::: "memory");
  __builtin_amdgcn_sched_barrier(0);
  __builtin_amdgcn_s_setprio(1);
#pragma unroll
  for (int i = 0; i < 4; ++i)
#pragma unroll
    for (int n = 0; n < 4; ++n)
      acc[i][n] = MFMA16(af[i], bf0[n], acc[i][n], 0, 0, 0);
  __builtin_amdgcn_s_setprio(0);
  __builtin_amdgcn_sched_barrier(0);
  __builtin_amdgcn_s_barrier();

  // ---- phase 2: kk=1, m0-3; load B kk1; stage A3(s+1)
#pragma unroll
  for (int i = 0; i < 4; ++i) af[i] = *(const bf16x8*)(Ard + i * 1024 + (cb ^ 32));
#pragma unroll
  for (int n = 0; n < 4; ++n) bf1[n] = *(const bf16x8*)(Brd + n * 1024 + (cb ^ 32));
  if (SN) async_g2l(aS + (size_t)192 * 8192 + k0n, nxtA + 3 * 4096 + stLds);
  __builtin_amdgcn_sched_barrier(0);
  __builtin_amdgcn_s_barrier();
  asm volatile("s_waitcnt lgkmcnt(0)" ::: "memory");
  __builtin_amdgcn_sched_barrier(0);
  __builtin_amdgcn_s_setprio(1);
#pragma unroll
  for (int i = 0; i < 4; ++i)
#pragma unroll
    for (int n = 0; n < 4; ++n)
      acc[i][n] = MFMA16(af[i], bf1[n], acc[i][n], 0, 0, 0);
  __builtin_amdgcn_s_setprio(0);
  __builtin_amdgcn_sched_barrier(0);
  __builtin_amdgcn_s_barrier();

  // ---- phase 3: kk=0, m4-7 (reuse bf0); stage A0,A2,B0,B1 of (s+2) into cur
#pragma unroll
  for (int i = 0; i < 4; ++i) af[i] = *(const bf16x8*)(Ard + (4 + i) * 1024 + cb);
  if (SN2) {
    async_g2l(aS + k0n2,                      curA + stLds);
    async_g2l(aS + (size_t)128 * 8192 + k0n2, curA + 2 * 4096 + stLds);
    async_g2l(bS + k0n2,                      curB + stLds);
    async_g2l(bS + (size_t)64 * 1024 + k0n2,  curB + 4096 + stLds);
  }
  __builtin_amdgcn_sched_barrier(0);
  __builtin_amdgcn_s_barrier();
  asm volatile("s_waitcnt lgkmcnt(0)" ::: "memory");
  __builtin_amdgcn_sched_barrier(0);
  __builtin_amdgcn_s_setprio(1);
#pragma unroll
  for (int i = 0; i < 4; ++i)
#pragma unroll
    for (int n = 0; n < 4; ++n)
      acc[4 + i][n] = MFMA16(af[i], bf0[n], acc[4 + i][n], 0, 0, 0);
  __builtin_amdgcn_s_setprio(0);
  __builtin_amdgcn_sched_barrier(0);
  __builtin_amdgcn_s_barrier();

  // ---- phase 4: kk=1, m4-7 (reuse bf1); stage B2,B3 of (s+2); counted vmcnt
#pragma unroll
  for (int i = 0; i < 4; ++i) af[i] = *(const bf16x8*)(Ard + (4 + i) * 1024 + (cb ^ 32));
  if (SN2) {
    async_g2l(bS + (size_t)128 * 1024 + k0n2, curB + 2 * 4096 + stLds);
    async_g2l(bS + (size_t)192 * 1024 + k0n2, curB + 3 * 4096 + stLds);
  }
  __builtin_amdgcn_sched_barrier(0);
  __builtin_amdgcn_s_barrier();
  asm volatile("s_waitcnt lgkmcnt(0)" ::: "memory");
  __builtin_amdgcn_sched_barrier(0);
  __builtin_amdgcn_s_setprio(1);
#pragma unroll
  for (int i = 0; i < 4; ++i)
#pragma unroll
    for (int n = 0; n < 4; ++n)
      acc[4 + i][n] = MFMA16(af[i], bf1[n], acc[4 + i][n], 0, 0, 0);
  __builtin_amdgcn_s_setprio(0);
  if (WV) {
    if (W0) asm volatile("s_waitcnt vmcnt(0)" ::: "memory");
    else    asm volatile("s_waitcnt vmcnt(6)" ::: "memory");
  }
  __builtin_amdgcn_sched_barrier(0);
  __builtin_amdgcn_s_barrier();
}

// 256x256 tile, BK=64, 8 waves (2M x 4N), double-buffered 128KB LDS,
// 4-phase/K-step counted-vmcnt pipeline. Grid: b(8) x mtile(4) x ntile(8);
// ntile<4 -> expert e0 cols, else e1. lin&7 = b keeps per-b working set
// on one XCD's L2.
__global__ __launch_bounds__(512, 2) void mlgemm_kernel(const ushort_t* __restrict__ xb,
                                                        const ushort_t* __restrict__ wt,
                                                        const int* __restrict__ selp,
                                                        const float* __restrict__ bias,
                                                        float* __restrict__ out) {
  __shared__ ushort_t As[2][256 * 64];   // 64KB
  __shared__ ushort_t Bs[2][256 * 64];   // 64KB

  const int lin = blockIdx.x;
  const int b = lin & 7;
  const int mtile = (lin >> 3) & 3;
  const int ntile = lin >> 5;
  const int e = (ntile < 4) ? read_sel(selp, 2 * b) : read_sel(selp, 2 * b + 1);
  const int n0e = (ntile & 3) * 256;
  const int m0 = mtile * 256;

  const int tid = threadIdx.x;
  const int lane = tid & 63;
  const int wv = tid >> 6;
  const int wm = wv >> 2;              // 0..1 (M half)
  const int wn = wv & 3;               // 0..3 (N quarter)
  const int frow = lane & 15;
  const int quad = lane >> 4;
  const int cb = ((quad ^ (lane & 7)) << 3);

  // staging: event = 64 rows x 64 k; thread t -> row t>>3, chunk (t&7)^((t>>3)&7)
  const int sr = tid >> 3;
  const int sch = (tid & 7) ^ (sr & 7);
  const ushort_t* aS = xb + (size_t)(m0 + sr) * (B_DIM * IN_DIM) + b * IN_DIM + sch * 8;
  const ushort_t* bS = wt + ((size_t)(e * OUT_DIM + n0e + sr)) * IN_DIM + sch * 8;
  const int stLds = wv * 512;          // wave-uniform LDS sub-base (8 rows/wave)

  const int ardo = (wm * 128 + frow) * 64;
  const int brdo = (wn * 64 + frow) * 64;

  f32x4 acc[8][4] = {};

  // prologue: tile0 (8 events -> buf0), tile1 partial (6 events -> buf1)
  async_g2l(aS,                           As[0] + stLds);
  async_g2l(aS + (size_t)64 * 8192,       As[0] + 4096 + stLds);
  async_g2l(aS + (size_t)128 * 8192,      As[0] + 2 * 4096 + stLds);
  async_g2l(aS + (size_t)192 * 8192,      As[0] + 3 * 4096 + stLds);
  async_g2l(bS,                           Bs[0] + stLds);
  async_g2l(bS + (size_t)64 * 1024,       Bs[0] + 4096 + stLds);
  async_g2l(bS + (size_t)128 * 1024,      Bs[0] + 2 * 4096 + stLds);
  async_g2l(bS + (size_t)192 * 1024,      Bs[0] + 3 * 4096 + stLds);
  __builtin_amdgcn_sched_barrier(0);
  async_g2l(aS + 64,                      As[1] + stLds);
  async_g2l(aS + (size_t)128 * 8192 + 64, As[1] + 2 * 4096 + stLds);
  async_g2l(bS + 64,                      Bs[1] + stLds);
  async_g2l(bS + (size_t)64 * 1024 + 64,  Bs[1] + 4096 + stLds);
  async_g2l(bS + (size_t)128 * 1024 + 64, Bs[1] + 2 * 4096 + stLds);
  async_g2l(bS + (size_t)192 * 1024 + 64, Bs[1] + 3 * 4096 + stLds);
  __builtin_amdgcn_sched_barrier(0);
  asm volatile("s_waitcnt vmcnt(6)" ::: "memory");
  __builtin_amdgcn_s_barrier();
  __builtin_amdgcn_sched_barrier(0);

  // steady state: steps 0..13 (vmcnt(6)); step 14 (vmcnt(0)); step 15 compute-only
  for (int s = 0; s < 14; s += 2) {
    gemm_step<true, true, true, false>(s,     As[0], Bs[0], As[1], Bs[1],
                                       aS, bS, stLds, ardo, brdo, cb, acc);
    gemm_step<true, true, true, false>(s + 1, As[1], Bs[1], As[0], Bs[0],
                                       aS, bS, stLds, ardo, brdo, cb, acc);
  }
  gemm_step<true, false, true, true>(14, As[0], Bs[0], As[1], Bs[1],
                                     aS, bS, stLds, ardo, brdo, cb, acc);
  gemm_step<false, false, false, false>(15, As[1], Bs[1], As[0], Bs[0],
                                        aS, bS, stLds, ardo, brdo, cb, acc);

  // epilogue: C/D map col=lane&15, row=quad*4+reg
  const float* bp = bias + (size_t)e * OUT_DIM + n0e + wn * 64 + frow;
  float bv[4];
#pragma unroll
  for (int n = 0; n < 4; ++n) bv[n] = bp[n * 16];
  const int colb = ntile * 256 + wn * 64 + frow;
  const int trow = m0 + wm * 128 + quad * 4;
  float* ob = out + (size_t)b * (K_SEL * OUT_DIM) + colb;
#pragma unroll
  for (int m = 0; m < 8; ++m) {
#pragma unroll
    for (int r = 0; r < 4; ++r) {
      float* orow = ob + (size_t)(trow + m * 16 + r) * (B_DIM * K_SEL * OUT_DIM);
#pragma unroll
      for (int n = 0; n < 4; ++n) orow[n * 16] = acc[m][n][r] + bv[n];
    }
  }
}

extern "C" void kernel_launch(void* const* d_in, const int* in_sizes, int n_in,
                              void* d_out, int out_size, void* d_ws, size_t ws_size,
                              hipStream_t stream) {
  const float* x    = (const float*)d_in[0];
  const int*   sel  = (const int*)d_in[1];
  const float* w    = (const float*)d_in[2];
  const float* bias = (const float*)d_in[3];
  float* out = (float*)d_out;

  ushort_t* xb = (ushort_t*)d_ws;                                   // 16 MB
  ushort_t* wt = (ushort_t*)((char*)d_ws +
                             (size_t)T_DIM * B_DIM * IN_DIM * 2);   // +32 MB

  convert_kernel<<<dim3(1024 + T_DIM * B_DIM * IN_DIM / 8 / 256), 256, 0, stream>>>(
      x, w, sel, xb, wt);
  mlgemm_kernel<<<dim3(8 * 4 * 8), 512, 0, stream>>>(xb, wt, sel, bias, out);
}